// Round 14
// baseline (238.299 us; speedup 1.0000x reference)
//
#include <hip/hip_runtime.h>

#define HH 16
#define DKK 64
#define SS 2048
#define BB 2
#define DD 1024

typedef __attribute__((ext_vector_type(4))) float f32x4;
typedef __attribute__((ext_vector_type(16))) float f32x16;
typedef __attribute__((ext_vector_type(8))) short bf16x8;
typedef __attribute__((ext_vector_type(4))) short s16x4;
typedef __attribute__((ext_vector_type(4))) int i32x4;

#define WAITCNT_VM0 0xF70  // vmcnt(0), ignore exp/lgkm

__device__ __forceinline__ short bf16b(float f) {
    union { float f; unsigned u; } x; x.f = f;
    unsigned r = (x.u + 0x7fffu + ((x.u >> 16) & 1u)) >> 16;
    return (short)r;
}

__device__ __forceinline__ f32x4 mfma16(bf16x8 a, bf16x8 b, f32x4 c) {
    return __builtin_amdgcn_mfma_f32_16x16x32_bf16(a, b, c, 0, 0, 0);
}

__device__ __forceinline__ f32x16 mfma32(bf16x8 a, bf16x8 b, f32x16 c) {
    return __builtin_amdgcn_mfma_f32_32x32x16_bf16(a, b, c, 0, 0, 0);
}

__device__ __forceinline__ void lds16(const short* g, short* l) {
    __builtin_amdgcn_global_load_lds(
        (const __attribute__((address_space(1))) void*)g,
        (__attribute__((address_space(3))) void*)l, 16, 0, 0);
}

// pack 2 f32 -> 1 dword of 2 bf16 (RNE)
__device__ __forceinline__ int cvtpk(float lo, float hi) {
    int r;
    asm("v_cvt_pk_bf16_f32 %0, %1, %2" : "=v"(r) : "v"(lo), "v"(hi));
    return r;
}

// swap a's upper 32 lanes with b's lower 32 lanes
__device__ __forceinline__ void swap32(int& a, int& b) {
    asm("v_permlane32_swap_b32 %0, %1" : "+v"(a), "+v"(b));
}

// ---------------- merged prologue: cast + transpose + bias in ONE launch ----------------
// blocks [0,4096): hs fp32->bf16; [4096,8192): weight transpose; [8192,8448): bias.
__global__ __launch_bounds__(256) void prep(
    const float* __restrict__ hs,
    const float* __restrict__ W0, const float* __restrict__ W1,
    const float* __restrict__ W2, const float* __restrict__ W3,
    const float* __restrict__ rb,
    short* __restrict__ hsb,
    short* __restrict__ T0, short* __restrict__ T1,
    short* __restrict__ T2, short* __restrict__ T3,
    float* __restrict__ tab) {
    __shared__ short tile[32][33];
    int blk = blockIdx.x, tid = threadIdx.x;
    if (blk < 4096) {
        int i = (blk * 256 + tid) * 4;
        f32x4 v = *(const f32x4*)(hs + i);
        s16x4 o;
        o.x = bf16b(v.x); o.y = bf16b(v.y); o.z = bf16b(v.z); o.w = bf16b(v.w);
        *(s16x4*)(hsb + i) = o;
    } else if (blk < 8192) {
        int t = blk - 4096;
        int z = t >> 10, r = t & 1023;
        int bx = r & 31, by = r >> 5;
        const float* W; short* T;
        switch (z) {
            case 0: W = W0; T = T0; break;
            case 1: W = W1; T = T1; break;
            case 2: W = W2; T = T2; break;
            default: W = W3; T = T3; break;
        }
        int n0 = bx * 32, k0 = by * 32;
        int tx = tid & 31, ty = (tid >> 5) * 4;
#pragma unroll
        for (int i = 0; i < 4; i++)
            tile[ty + i][tx] = bf16b(W[(k0 + ty + i) * DD + n0 + tx]);
        __syncthreads();
#pragma unroll
        for (int i = 0; i < 4; i++)
            T[(n0 + ty + i) * DD + k0 + tx] = tile[tx][ty + i];
    } else {
        int idx = (blk - 8192) * 256 + tid;
        if (idx < HH * 4095) {
            int h = idx / 4095, d = idx % 4095;
            int rel = d - 2047; // k - q
            int bucket = (rel > 0) ? 16 : 0;
            unsigned rr = (rel < 0) ? (unsigned)(-rel) : (unsigned)rel;
            int add;
            if (rr < 8) add = (int)rr;
            else {
                int e = 31 - __clz(rr);
                unsigned long long r2 = (unsigned long long)rr * (unsigned long long)rr;
                int f = 2 * e + ((r2 >= (2ull << (2 * e))) ? 1 : 0);
                add = 8 + (f - 6);
                if (add > 15) add = 15;
            }
            bucket += add;
            tab[h * 4095 + d] = rb[bucket * HH + h] * 1.44269504f;
        }
    }
}

// ---------------- fused QKV GEMM (r21 DIAGNOSTIC: r20 BK=64 body run 2x) -------------
// 13 rounds of non-attn theories were counter-blind: attn (59us) occupies the
// whole top-5 dispatch list, so gemm_qkv's MfmaUtil/conflicts/dur were NEVER
// observed. This round runs the K-loop twice: rep-0's acc is kept live via an
// empty asm sink (anti-DCE), re-zeroed, rep-1 recomputes from zero -> stored
// output is BIT-IDENTICAL, duration ~2x -> gemm_qkv tops the dispatch list and
// exposes its true counters. Sacrificial round; best kernel remains r20.
// Round-15 decision table: MfmaUtil>40% -> structural ceiling (rewrite or
// accept); <25%+VALUBusy high -> epilogue-bound; conflicts>>1M -> BK=64 read
// swizzle broken; true dur<=40us -> time is in gemm_out/prep/launch gaps.
__global__ __launch_bounds__(256) void gemm_qkv(
    const short* __restrict__ A, const short* __restrict__ Wt,
    short* __restrict__ Cq, short* __restrict__ Ck, short* __restrict__ Cvt) {
    const int K = 1024;
    __shared__ short As[128 * 64];
    __shared__ short Bs[128 * 64];
    int tid = threadIdx.x;
    int wave = tid >> 6, lane = tid & 63;
    int quad = lane >> 4, l16 = lane & 15;
    int m0 = blockIdx.y * 128, n0 = blockIdx.x * 128;

    int wm = (wave & 1) * 64, wn = (wave >> 1) * 64;
    int r0 = tid >> 3;                         // row 0..31 within 32-row call
    int c0 = ((tid & 7) ^ (r0 & 7)) * 8;       // pre-swizzled global chunk
    int ex7 = l16 & 7;

    f32x4 acc[4][4];
#pragma unroll
    for (int i = 0; i < 4; i++)
#pragma unroll
        for (int j = 0; j < 4; j++) acc[i][j] = (f32x4){0.f, 0.f, 0.f, 0.f};

    for (int rep = 0; rep < 2; rep++) {
        if (rep) {
            // keep rep-0 result live (no DCE), then restart from zero so the
            // stored rep-1 result is bit-identical to a single pass.
#pragma unroll
            for (int i = 0; i < 4; i++)
#pragma unroll
                for (int j = 0; j < 4; j++) {
                    asm volatile("" :: "v"(acc[i][j][0]), "v"(acc[i][j][1]),
                                       "v"(acc[i][j][2]), "v"(acc[i][j][3]));
                    acc[i][j] = (f32x4){0.f, 0.f, 0.f, 0.f};
                }
        }
        for (int k0 = 0; k0 < K; k0 += 64) {
            __syncthreads();
#pragma unroll
            for (int j = 0; j < 4; j++) {
                lds16(A + (size_t)(m0 + j * 32 + r0) * K + k0 + c0,
                      As + j * 2048 + wave * 512);
                lds16(Wt + (size_t)(n0 + j * 32 + r0) * K + k0 + c0,
                      Bs + j * 2048 + wave * 512);
            }
            __syncthreads();
#pragma unroll
            for (int kh = 0; kh < 2; kh++) {
                bf16x8 af[4], bfr[4];
#pragma unroll
                for (int t = 0; t < 4; t++) {
                    int sl = (((kh * 4 + quad) ^ ex7)) * 8;
                    af[t] = *(const bf16x8*)(As + (wm + t * 16 + l16) * 64 + sl);
                    bfr[t] = *(const bf16x8*)(Bs + (wn + t * 16 + l16) * 64 + sl);
                }
#pragma unroll
                for (int mt = 0; mt < 4; mt++)
#pragma unroll
                    for (int nt = 0; nt < 4; nt++)
                        acc[mt][nt] = mfma16(af[mt], bfr[nt], acc[mt][nt]);
            }
        }
    }

#pragma unroll
    for (int mt = 0; mt < 4; mt++) {
#pragma unroll
        for (int nt = 0; nt < 4; nt++) {
#pragma unroll
            for (int r = 0; r < 4; r++) {
                int gm = m0 + wm + mt * 16 + quad * 4 + r;
                int gn = n0 + wn + nt * 16 + l16;
                int b = gm >> 11, s = gm & 2047;
                int which = gn >> 10;       // wave-uniform per nt
                int h = (gn >> 6) & 15, dk = gn & 63;
                short bv = bf16b(acc[mt][nt][r]);
                if (which == 0)
                    Cq[(((size_t)(b * HH + h)) * SS + s) * DKK + dk] = bv;
                else if (which == 1)
                    Ck[(((size_t)(b * HH + h)) * SS + s) * DKK + dk] = bv;
                else
                    Cvt[(((size_t)(b * HH + h)) * DKK + dk) * SS + s] = bv;
            }
        }
    }
}

// ---------------- output projection (r20: BK=64): C[4096][1024] fp32 = A * WoT^T ----
__global__ __launch_bounds__(256) void gemm_out(
    const short* __restrict__ A, const short* __restrict__ Wt,
    float* __restrict__ Cout) {
    const int K = 1024, N = 1024;
    __shared__ short As[64 * 64];
    __shared__ short Bs[128 * 64];
    int tid = threadIdx.x;
    int wave = tid >> 6, lane = tid & 63;
    int quad = lane >> 4, l16 = lane & 15;
    int m0 = blockIdx.y * 64, n0 = blockIdx.x * 128;

    int wm = (wave & 1) * 32, wn = (wave >> 1) * 64;
    int r0 = tid >> 3;
    int c0 = ((tid & 7) ^ (r0 & 7)) * 8;
    int ex7 = l16 & 7;

    f32x4 acc[2][4];
#pragma unroll
    for (int i = 0; i < 2; i++)
#pragma unroll
        for (int j = 0; j < 4; j++) acc[i][j] = (f32x4){0.f, 0.f, 0.f, 0.f};

    for (int k0 = 0; k0 < K; k0 += 64) {
        __syncthreads();
#pragma unroll
        for (int j = 0; j < 2; j++)
            lds16(A + (size_t)(m0 + j * 32 + r0) * K + k0 + c0,
                  As + j * 2048 + wave * 512);
#pragma unroll
        for (int j = 0; j < 4; j++)
            lds16(Wt + (size_t)(n0 + j * 32 + r0) * K + k0 + c0,
                  Bs + j * 2048 + wave * 512);
        __syncthreads();
#pragma unroll
        for (int kh = 0; kh < 2; kh++) {
            bf16x8 af[2], bfr[4];
            int sl = (((kh * 4 + quad) ^ ex7)) * 8;
#pragma unroll
            for (int t = 0; t < 2; t++)
                af[t] = *(const bf16x8*)(As + (wm + t * 16 + l16) * 64 + sl);
#pragma unroll
            for (int t = 0; t < 4; t++)
                bfr[t] = *(const bf16x8*)(Bs + (wn + t * 16 + l16) * 64 + sl);
#pragma unroll
            for (int mt = 0; mt < 2; mt++)
#pragma unroll
                for (int nt = 0; nt < 4; nt++)
                    acc[mt][nt] = mfma16(af[mt], bfr[nt], acc[mt][nt]);
        }
    }

#pragma unroll
    for (int mt = 0; mt < 2; mt++)
#pragma unroll
        for (int nt = 0; nt < 4; nt++)
#pragma unroll
            for (int r = 0; r < 4; r++) {
                int gm = m0 + wm + mt * 16 + quad * 4 + r;
                int gn = n0 + wn + nt * 16 + l16;
                Cout[(size_t)gm * N + gn] = acc[mt][nt][r];
            }
}

// ---------------- attention (r11-exact: verified best; at its latency floor) ---------
__global__ __launch_bounds__(256, 2) void attn(
    const short* __restrict__ Q, const short* __restrict__ Kmat,
    const short* __restrict__ Vt, const float* __restrict__ btab,
    short* __restrict__ O) {
    __shared__ short Ks[2][64 * 64];
    __shared__ short Vs[2][64 * 64];
    __shared__ float Linv[4][32];

    int tid = threadIdx.x;
    int wave = tid >> 6, lane = tid & 63;
    int el = lane & 31, hi = lane >> 5;
    int ex7 = el & 7;
    int bh = blockIdx.x;
    int h = bh & 15, b = bh >> 4;
    int q0b = blockIdx.y * 128;
    int q0w = q0b + wave * 32;

    const short* Qb = Q + (size_t)bh * SS * DKK;
    const short* Kb = Kmat + (size_t)bh * SS * DKK;
    const short* Vb = Vt + (size_t)bh * DKK * SS;
    const float* bt = btab + h * 4095;

    float blo = bt[2047 - 128];
    float bhi = bt[2047 + 128];

    // staging: row kro, 16B slot (tid&7), global slot XOR'd by row&7
    int kro = tid >> 3;
    int gk = (tid & 7) ^ (kro & 7);
    const short* Kg0 = Kb + (size_t)kro * DKK + gk * 8;
    const short* Kg1 = Kb + (size_t)(kro + 32) * DKK + gk * 8;
    const short* Vg0 = Vb + (size_t)kro * SS + gk * 8;
    const short* Vg1 = Vb + (size_t)(kro + 32) * SS + gk * 8;

    // Q as B-fragments (held in registers): lane needs Q[q0w+el][c*16 + hi*8 + j]
    bf16x8 qB[4];
#pragma unroll
    for (int c = 0; c < 4; c++)
        qB[c] = *(const bf16x8*)(Qb + (size_t)(q0w + el) * DKK + c * 16 + hi * 8);

    f32x16 o0, o1;  // dk chunks [0,32) and [32,64); rows = q
#pragma unroll
    for (int i = 0; i < 16; i++) { o0[i] = 0.f; o1[i] = 0.f; }
    float ls0 = 0.f, ls1 = 0.f, ls2 = 0.f, ls3 = 0.f;

    int bq = 2047 - q0w - el;  // bias index base: d = bq + k

    lds16(Kg0, &Ks[0][wave * 512]);
    lds16(Kg1, &Ks[0][2048 + wave * 512]);
    lds16(Vg0, &Vs[0][wave * 512]);
    lds16(Vg1, &Vs[0][2048 + wave * 512]);

    int cur = 0;
    for (int kc = 0; kc < SS; kc += 64) {
        __syncthreads();
        int kn = (kc + 64) & (SS - 1);
        int nxt = cur ^ 1;
        lds16(Kg0 + (size_t)kn * DKK, &Ks[nxt][wave * 512]);
        lds16(Kg1 + (size_t)kn * DKK, &Ks[nxt][2048 + wave * 512]);
        lds16(Vg0 + kn, &Vs[nxt][wave * 512]);
        lds16(Vg1 + kn, &Vs[nxt][2048 + wave * 512]);

        const short* Ksc = &Ks[cur][0];
        const short* Vsc = &Vs[cur][0];

        // V B-fragments: vf[kchunk][m] = V[kchunk*16 + hi*8 + j][m*32 + el]
        bf16x8 vf[4][2];
#pragma unroll
        for (int c4 = 0; c4 < 4; c4++)
#pragma unroll
            for (int m = 0; m < 2; m++)
                vf[c4][m] = *(const bf16x8*)(
                    Vsc + (m * 32 + el) * 64 + (((2 * c4 + hi) ^ ex7) * 8));

#pragma unroll
        for (int st = 0; st < 2; st++) {
            // QK^T for k-strip [kc+st*32, +32): D[k][q], lane col = q = el
            f32x16 acc;
#pragma unroll
            for (int i = 0; i < 16; i++) acc[i] = 0.f;
#pragma unroll
            for (int c = 0; c < 4; c++) {
                bf16x8 kA = *(const bf16x8*)(
                    Ksc + (st * 32 + el) * 64 + (((2 * c + hi) ^ ex7) * 8));
                acc = mfma32(kA, qB[c], acc);
            }

            int ks = kc + st * 32;
            float br[16];
            if (ks > q0w - 159 && ks < q0w + 159) {
                // some |k-q| < 128 possible: read table (index in [1858,2236], safe)
#pragma unroll
                for (int r = 0; r < 16; r++)
                    br[r] = bt[bq + ks + ((r & 3) + 8 * (r >> 2) + 4 * hi)];
            } else {
                float bc = (ks <= q0w - 159) ? blo : bhi;
#pragma unroll
                for (int r = 0; r < 16; r++) br[r] = bc;
            }

            float p[16];
#pragma unroll
            for (int r = 0; r < 16; r++)
                p[r] = __builtin_amdgcn_exp2f(
                    fmaf(acc[r], 1.44269504f, br[r]));
#pragma unroll
            for (int r = 0; r < 16; r += 4) {
                ls0 += p[r]; ls1 += p[r + 1]; ls2 += p[r + 2]; ls3 += p[r + 3];
            }

            // pack own 16 p and swap halves -> PV A-fragments (T12)
            int A1 = cvtpk(p[0], p[1]),   A2 = cvtpk(p[2], p[3]);
            int B1 = cvtpk(p[4], p[5]),   B2 = cvtpk(p[6], p[7]);
            int C1 = cvtpk(p[8], p[9]),   C2 = cvtpk(p[10], p[11]);
            int D1 = cvtpk(p[12], p[13]), D2 = cvtpk(p[14], p[15]);
            swap32(A1, B1); swap32(A2, B2);
            swap32(C1, D1); swap32(C2, D2);
            bf16x8 pf0 = __builtin_bit_cast(bf16x8, (i32x4){A1, A2, B1, B2});
            bf16x8 pf1 = __builtin_bit_cast(bf16x8, (i32x4){C1, C2, D1, D2});

            // PV: o[q][dk] += P[q][k] * V[k][dk]
            o0 = mfma32(pf0, vf[st * 2 + 0][0], o0);
            o1 = mfma32(pf0, vf[st * 2 + 0][1], o1);
            o0 = mfma32(pf1, vf[st * 2 + 1][0], o0);
            o1 = mfma32(pf1, vf[st * 2 + 1][1], o1);
        }
        cur ^= 1;
    }
    __builtin_amdgcn_s_waitcnt(WAITCNT_VM0); // wrapped DMAs land before retirement

    // row sums: lane (el,hi) holds sum over its k-half for q = q0w+el
    float lsum = (ls0 + ls1) + (ls2 + ls3);
    float tot = lsum + __shfl_xor(lsum, 32);
    float inv = 1.f / tot;
    if (hi == 0) Linv[wave][el] = inv;
    __asm__ __volatile__("" ::: "memory");

#pragma unroll
    for (int r = 0; r < 16; r++) {
        int qm = (r & 3) + 8 * (r >> 2) + 4 * hi;
        float iv = Linv[wave][qm];  // broadcast read, conflict-free
        size_t base = ((size_t)(b * SS + q0w + qm)) * (HH * DKK) + h * DKK;
        O[base + el] = bf16b(o0[r] * iv);
        O[base + 32 + el] = bf16b(o1[r] * iv);
    }
}

extern "C" void kernel_launch(void* const* d_in, const int* in_sizes, int n_in,
                              void* d_out, int out_size, void* d_ws, size_t ws_size,
                              hipStream_t stream) {
    const float* hs = (const float*)d_in[0];
    const float* Wq = (const float*)d_in[1];
    const float* Wk = (const float*)d_in[2];
    const float* Wv = (const float*)d_in[3];
    const float* Wo = (const float*)d_in[4];
    const float* rb = (const float*)d_in[5];
    float* out = (float*)d_out;

    char* ws = (char*)d_ws;
    size_t off = 0;
    auto alloc = [&](size_t bytes) -> void* {
        void* p = (void*)(ws + off);
        off += (bytes + 255) & ~(size_t)255;
        return p;
    };
    const size_t M = (size_t)BB * SS; // 4096
    short* hsb = (short*)alloc(M * DD * 2);
    // WqT/WkT/WvT MUST stay contiguous (2MB each, 256-aligned -> no padding):
    // gemm_qkv reads them as one [3072][1024] matrix.
    short* WqT = (short*)alloc((size_t)DD * DD * 2);
    short* WkT = (short*)alloc((size_t)DD * DD * 2);
    short* WvT = (short*)alloc((size_t)DD * DD * 2);
    short* WoT = (short*)alloc((size_t)DD * DD * 2);
    short* Qb  = (short*)alloc(M * DD * 2);
    short* Kb  = (short*)alloc(M * DD * 2);
    short* VTb = (short*)alloc(M * DD * 2);
    short* Ab  = (short*)alloc(M * DD * 2);
    float* btab = (float*)alloc((size_t)HH * 4095 * 4);

    prep<<<8448, 256, 0, stream>>>(hs, Wq, Wk, Wv, Wo, rb,
                                   hsb, WqT, WkT, WvT, WoT, btab);
    gemm_qkv<<<dim3(24, 32), 256, 0, stream>>>(hsb, WqT, Qb, Kb, VTb);
    attn<<<dim3(32, 16), 256, 0, stream>>>(Qb, Kb, VTb, btab, Ab);
    gemm_out<<<dim3(8, 64), 256, 0, stream>>>(Ab, WoT, out);
}

// Round 15
// 198.957 us; speedup vs baseline: 1.1977x; 1.1977x over previous
//
#include <hip/hip_runtime.h>

#define HH 16
#define DKK 64
#define SS 2048
#define BB 2
#define DD 1024

typedef __attribute__((ext_vector_type(4))) float f32x4;
typedef __attribute__((ext_vector_type(16))) float f32x16;
typedef __attribute__((ext_vector_type(8))) short bf16x8;
typedef __attribute__((ext_vector_type(4))) short s16x4;
typedef __attribute__((ext_vector_type(4))) int i32x4;

#define WAITCNT_VM0 0xF70  // vmcnt(0), ignore exp/lgkm

__device__ __forceinline__ short bf16b(float f) {
    union { float f; unsigned u; } x; x.f = f;
    unsigned r = (x.u + 0x7fffu + ((x.u >> 16) & 1u)) >> 16;
    return (short)r;
}

__device__ __forceinline__ f32x4 mfma16(bf16x8 a, bf16x8 b, f32x4 c) {
    return __builtin_amdgcn_mfma_f32_16x16x32_bf16(a, b, c, 0, 0, 0);
}

__device__ __forceinline__ f32x16 mfma32(bf16x8 a, bf16x8 b, f32x16 c) {
    return __builtin_amdgcn_mfma_f32_32x32x16_bf16(a, b, c, 0, 0, 0);
}

__device__ __forceinline__ void lds16(const short* g, short* l) {
    __builtin_amdgcn_global_load_lds(
        (const __attribute__((address_space(1))) void*)g,
        (__attribute__((address_space(3))) void*)l, 16, 0, 0);
}

// pack 2 f32 -> 1 dword of 2 bf16 (RNE)
__device__ __forceinline__ int cvtpk(float lo, float hi) {
    int r;
    asm("v_cvt_pk_bf16_f32 %0, %1, %2" : "=v"(r) : "v"(lo), "v"(hi));
    return r;
}

// swap a's upper 32 lanes with b's lower 32 lanes
__device__ __forceinline__ void swap32(int& a, int& b) {
    asm("v_permlane32_swap_b32 %0, %1" : "+v"(a), "+v"(b));
}

// ---------------- merged prologue: cast + transpose + bias in ONE launch ----------------
// blocks [0,4096): hs fp32->bf16; [4096,8192): weight transpose; [8192,8448): bias.
__global__ __launch_bounds__(256) void prep(
    const float* __restrict__ hs,
    const float* __restrict__ W0, const float* __restrict__ W1,
    const float* __restrict__ W2, const float* __restrict__ W3,
    const float* __restrict__ rb,
    short* __restrict__ hsb,
    short* __restrict__ T0, short* __restrict__ T1,
    short* __restrict__ T2, short* __restrict__ T3,
    float* __restrict__ tab) {
    __shared__ short tile[32][33];
    int blk = blockIdx.x, tid = threadIdx.x;
    if (blk < 4096) {
        int i = (blk * 256 + tid) * 4;
        f32x4 v = *(const f32x4*)(hs + i);
        s16x4 o;
        o.x = bf16b(v.x); o.y = bf16b(v.y); o.z = bf16b(v.z); o.w = bf16b(v.w);
        *(s16x4*)(hsb + i) = o;
    } else if (blk < 8192) {
        int t = blk - 4096;
        int z = t >> 10, r = t & 1023;
        int bx = r & 31, by = r >> 5;
        const float* W; short* T;
        switch (z) {
            case 0: W = W0; T = T0; break;
            case 1: W = W1; T = T1; break;
            case 2: W = W2; T = T2; break;
            default: W = W3; T = T3; break;
        }
        int n0 = bx * 32, k0 = by * 32;
        int tx = tid & 31, ty = (tid >> 5) * 4;
#pragma unroll
        for (int i = 0; i < 4; i++)
            tile[ty + i][tx] = bf16b(W[(k0 + ty + i) * DD + n0 + tx]);
        __syncthreads();
#pragma unroll
        for (int i = 0; i < 4; i++)
            T[(n0 + ty + i) * DD + k0 + tx] = tile[tx][ty + i];
    } else {
        int idx = (blk - 8192) * 256 + tid;
        if (idx < HH * 4095) {
            int h = idx / 4095, d = idx % 4095;
            int rel = d - 2047; // k - q
            int bucket = (rel > 0) ? 16 : 0;
            unsigned rr = (rel < 0) ? (unsigned)(-rel) : (unsigned)rel;
            int add;
            if (rr < 8) add = (int)rr;
            else {
                int e = 31 - __clz(rr);
                unsigned long long r2 = (unsigned long long)rr * (unsigned long long)rr;
                int f = 2 * e + ((r2 >= (2ull << (2 * e))) ? 1 : 0);
                add = 8 + (f - 6);
                if (add > 15) add = 15;
            }
            bucket += add;
            tab[h * 4095 + d] = rb[bucket * HH + h] * 1.44269504f;
        }
    }
}

// ---------------- fused QKV GEMM (r22: 64x128 tile, 6 blocks/CU) ---------------------
// r21 diagnostic: MfmaUtil 21% (= FLOP/peak exactly; 4.8x above MFMA floor),
// VALUBusy 28%, conflicts 0, FETCH 66MB (~10us HBM) -> latency-bound with only
// 3 independent blocks/CU (grid 768, barrier-locked waves within block).
// r22: halve the m-tile -> 64x128, 4 waves of 32x64 (acc 2x4), LDS 24KB,
// grid (24,64) = 1536 blocks = 6/CU: 2x independent streams/CU. Per-work
// MFMA/VALU unchanged; A-staging +50% (L3-absorbed). Same r20-verified BK=64
// index algebra (swizzle invariant row&7 == l16&7 preserved).
__global__ __launch_bounds__(256) void gemm_qkv(
    const short* __restrict__ A, const short* __restrict__ Wt,
    short* __restrict__ Cq, short* __restrict__ Ck, short* __restrict__ Cvt) {
    const int K = 1024;
    __shared__ short As[64 * 64];
    __shared__ short Bs[128 * 64];
    int tid = threadIdx.x;
    int wave = tid >> 6, lane = tid & 63;
    int quad = lane >> 4, l16 = lane & 15;
    int m0 = blockIdx.y * 64, n0 = blockIdx.x * 128;

    int wm = (wave & 1) * 32, wn = (wave >> 1) * 64;
    int r0 = tid >> 3;                         // row 0..31 within 32-row round
    int c0 = ((tid & 7) ^ (r0 & 7)) * 8;       // pre-swizzled global chunk
    int ex7 = l16 & 7;

    f32x4 acc[2][4];
#pragma unroll
    for (int i = 0; i < 2; i++)
#pragma unroll
        for (int j = 0; j < 4; j++) acc[i][j] = (f32x4){0.f, 0.f, 0.f, 0.f};

    for (int k0 = 0; k0 < K; k0 += 64) {
        __syncthreads();
#pragma unroll
        for (int j = 0; j < 2; j++)
            lds16(A + (size_t)(m0 + j * 32 + r0) * K + k0 + c0,
                  As + j * 2048 + wave * 512);
#pragma unroll
        for (int j = 0; j < 4; j++)
            lds16(Wt + (size_t)(n0 + j * 32 + r0) * K + k0 + c0,
                  Bs + j * 2048 + wave * 512);
        __syncthreads();
#pragma unroll
        for (int kh = 0; kh < 2; kh++) {
            int sl = ((kh * 4 + quad) ^ ex7) * 8;
            bf16x8 af[2], bfr[4];
#pragma unroll
            for (int t = 0; t < 2; t++)
                af[t] = *(const bf16x8*)(As + (wm + t * 16 + l16) * 64 + sl);
#pragma unroll
            for (int t = 0; t < 4; t++)
                bfr[t] = *(const bf16x8*)(Bs + (wn + t * 16 + l16) * 64 + sl);
#pragma unroll
            for (int mt = 0; mt < 2; mt++)
#pragma unroll
                for (int nt = 0; nt < 4; nt++)
                    acc[mt][nt] = mfma16(af[mt], bfr[nt], acc[mt][nt]);
        }
    }

#pragma unroll
    for (int mt = 0; mt < 2; mt++) {
#pragma unroll
        for (int nt = 0; nt < 4; nt++) {
#pragma unroll
            for (int r = 0; r < 4; r++) {
                int gm = m0 + wm + mt * 16 + quad * 4 + r;
                int gn = n0 + wn + nt * 16 + l16;
                int b = gm >> 11, s = gm & 2047;
                int which = gn >> 10;       // wave-uniform per nt
                int h = (gn >> 6) & 15, dk = gn & 63;
                short bv = bf16b(acc[mt][nt][r]);
                if (which == 0)
                    Cq[(((size_t)(b * HH + h)) * SS + s) * DKK + dk] = bv;
                else if (which == 1)
                    Ck[(((size_t)(b * HH + h)) * SS + s) * DKK + dk] = bv;
                else
                    Cvt[(((size_t)(b * HH + h)) * DKK + dk) * SS + s] = bv;
            }
        }
    }
}

// ---------------- output projection (r22: 64x64 tile, 4 blocks/CU) -------------------
__global__ __launch_bounds__(256) void gemm_out(
    const short* __restrict__ A, const short* __restrict__ Wt,
    float* __restrict__ Cout) {
    const int K = 1024, N = 1024;
    __shared__ short As[64 * 64];
    __shared__ short Bs[64 * 64];
    int tid = threadIdx.x;
    int wave = tid >> 6, lane = tid & 63;
    int quad = lane >> 4, l16 = lane & 15;
    int m0 = blockIdx.y * 64, n0 = blockIdx.x * 64;

    int wm = (wave & 1) * 32, wn = (wave >> 1) * 32;
    int r0 = tid >> 3;
    int c0 = ((tid & 7) ^ (r0 & 7)) * 8;
    int ex7 = l16 & 7;

    f32x4 acc[2][2];
#pragma unroll
    for (int i = 0; i < 2; i++)
#pragma unroll
        for (int j = 0; j < 2; j++) acc[i][j] = (f32x4){0.f, 0.f, 0.f, 0.f};

    for (int k0 = 0; k0 < K; k0 += 64) {
        __syncthreads();
#pragma unroll
        for (int j = 0; j < 2; j++) {
            lds16(A + (size_t)(m0 + j * 32 + r0) * K + k0 + c0,
                  As + j * 2048 + wave * 512);
            lds16(Wt + (size_t)(n0 + j * 32 + r0) * K + k0 + c0,
                  Bs + j * 2048 + wave * 512);
        }
        __syncthreads();
#pragma unroll
        for (int kh = 0; kh < 2; kh++) {
            int sl = ((kh * 4 + quad) ^ ex7) * 8;
            bf16x8 af[2], bfr[2];
#pragma unroll
            for (int t = 0; t < 2; t++) {
                af[t] = *(const bf16x8*)(As + (wm + t * 16 + l16) * 64 + sl);
                bfr[t] = *(const bf16x8*)(Bs + (wn + t * 16 + l16) * 64 + sl);
            }
#pragma unroll
            for (int mt = 0; mt < 2; mt++)
#pragma unroll
                for (int nt = 0; nt < 2; nt++)
                    acc[mt][nt] = mfma16(af[mt], bfr[nt], acc[mt][nt]);
        }
    }

#pragma unroll
    for (int mt = 0; mt < 2; mt++)
#pragma unroll
        for (int nt = 0; nt < 2; nt++)
#pragma unroll
            for (int r = 0; r < 4; r++) {
                int gm = m0 + wm + mt * 16 + quad * 4 + r;
                int gn = n0 + wn + nt * 16 + l16;
                Cout[(size_t)gm * N + gn] = acc[mt][nt][r];
            }
}

// ---------------- attention (r11-exact: verified best; at its latency floor) ---------
__global__ __launch_bounds__(256, 2) void attn(
    const short* __restrict__ Q, const short* __restrict__ Kmat,
    const short* __restrict__ Vt, const float* __restrict__ btab,
    short* __restrict__ O) {
    __shared__ short Ks[2][64 * 64];
    __shared__ short Vs[2][64 * 64];
    __shared__ float Linv[4][32];

    int tid = threadIdx.x;
    int wave = tid >> 6, lane = tid & 63;
    int el = lane & 31, hi = lane >> 5;
    int ex7 = el & 7;
    int bh = blockIdx.x;
    int h = bh & 15, b = bh >> 4;
    int q0b = blockIdx.y * 128;
    int q0w = q0b + wave * 32;

    const short* Qb = Q + (size_t)bh * SS * DKK;
    const short* Kb = Kmat + (size_t)bh * SS * DKK;
    const short* Vb = Vt + (size_t)bh * DKK * SS;
    const float* bt = btab + h * 4095;

    float blo = bt[2047 - 128];
    float bhi = bt[2047 + 128];

    // staging: row kro, 16B slot (tid&7), global slot XOR'd by row&7
    int kro = tid >> 3;
    int gk = (tid & 7) ^ (kro & 7);
    const short* Kg0 = Kb + (size_t)kro * DKK + gk * 8;
    const short* Kg1 = Kb + (size_t)(kro + 32) * DKK + gk * 8;
    const short* Vg0 = Vb + (size_t)kro * SS + gk * 8;
    const short* Vg1 = Vb + (size_t)(kro + 32) * SS + gk * 8;

    // Q as B-fragments (held in registers): lane needs Q[q0w+el][c*16 + hi*8 + j]
    bf16x8 qB[4];
#pragma unroll
    for (int c = 0; c < 4; c++)
        qB[c] = *(const bf16x8*)(Qb + (size_t)(q0w + el) * DKK + c * 16 + hi * 8);

    f32x16 o0, o1;  // dk chunks [0,32) and [32,64); rows = q
#pragma unroll
    for (int i = 0; i < 16; i++) { o0[i] = 0.f; o1[i] = 0.f; }
    float ls0 = 0.f, ls1 = 0.f, ls2 = 0.f, ls3 = 0.f;

    int bq = 2047 - q0w - el;  // bias index base: d = bq + k

    lds16(Kg0, &Ks[0][wave * 512]);
    lds16(Kg1, &Ks[0][2048 + wave * 512]);
    lds16(Vg0, &Vs[0][wave * 512]);
    lds16(Vg1, &Vs[0][2048 + wave * 512]);

    int cur = 0;
    for (int kc = 0; kc < SS; kc += 64) {
        __syncthreads();
        int kn = (kc + 64) & (SS - 1);
        int nxt = cur ^ 1;
        lds16(Kg0 + (size_t)kn * DKK, &Ks[nxt][wave * 512]);
        lds16(Kg1 + (size_t)kn * DKK, &Ks[nxt][2048 + wave * 512]);
        lds16(Vg0 + kn, &Vs[nxt][wave * 512]);
        lds16(Vg1 + kn, &Vs[nxt][2048 + wave * 512]);

        const short* Ksc = &Ks[cur][0];
        const short* Vsc = &Vs[cur][0];

        // V B-fragments: vf[kchunk][m] = V[kchunk*16 + hi*8 + j][m*32 + el]
        bf16x8 vf[4][2];
#pragma unroll
        for (int c4 = 0; c4 < 4; c4++)
#pragma unroll
            for (int m = 0; m < 2; m++)
                vf[c4][m] = *(const bf16x8*)(
                    Vsc + (m * 32 + el) * 64 + (((2 * c4 + hi) ^ ex7) * 8));

#pragma unroll
        for (int st = 0; st < 2; st++) {
            // QK^T for k-strip [kc+st*32, +32): D[k][q], lane col = q = el
            f32x16 acc;
#pragma unroll
            for (int i = 0; i < 16; i++) acc[i] = 0.f;
#pragma unroll
            for (int c = 0; c < 4; c++) {
                bf16x8 kA = *(const bf16x8*)(
                    Ksc + (st * 32 + el) * 64 + (((2 * c + hi) ^ ex7) * 8));
                acc = mfma32(kA, qB[c], acc);
            }

            int ks = kc + st * 32;
            float br[16];
            if (ks > q0w - 159 && ks < q0w + 159) {
                // some |k-q| < 128 possible: read table (index in [1858,2236], safe)
#pragma unroll
                for (int r = 0; r < 16; r++)
                    br[r] = bt[bq + ks + ((r & 3) + 8 * (r >> 2) + 4 * hi)];
            } else {
                float bc = (ks <= q0w - 159) ? blo : bhi;
#pragma unroll
                for (int r = 0; r < 16; r++) br[r] = bc;
            }

            float p[16];
#pragma unroll
            for (int r = 0; r < 16; r++)
                p[r] = __builtin_amdgcn_exp2f(
                    fmaf(acc[r], 1.44269504f, br[r]));
#pragma unroll
            for (int r = 0; r < 16; r += 4) {
                ls0 += p[r]; ls1 += p[r + 1]; ls2 += p[r + 2]; ls3 += p[r + 3];
            }

            // pack own 16 p and swap halves -> PV A-fragments (T12)
            int A1 = cvtpk(p[0], p[1]),   A2 = cvtpk(p[2], p[3]);
            int B1 = cvtpk(p[4], p[5]),   B2 = cvtpk(p[6], p[7]);
            int C1 = cvtpk(p[8], p[9]),   C2 = cvtpk(p[10], p[11]);
            int D1 = cvtpk(p[12], p[13]), D2 = cvtpk(p[14], p[15]);
            swap32(A1, B1); swap32(A2, B2);
            swap32(C1, D1); swap32(C2, D2);
            bf16x8 pf0 = __builtin_bit_cast(bf16x8, (i32x4){A1, A2, B1, B2});
            bf16x8 pf1 = __builtin_bit_cast(bf16x8, (i32x4){C1, C2, D1, D2});

            // PV: o[q][dk] += P[q][k] * V[k][dk]
            o0 = mfma32(pf0, vf[st * 2 + 0][0], o0);
            o1 = mfma32(pf0, vf[st * 2 + 0][1], o1);
            o0 = mfma32(pf1, vf[st * 2 + 1][0], o0);
            o1 = mfma32(pf1, vf[st * 2 + 1][1], o1);
        }
        cur ^= 1;
    }
    __builtin_amdgcn_s_waitcnt(WAITCNT_VM0); // wrapped DMAs land before retirement

    // row sums: lane (el,hi) holds sum over its k-half for q = q0w+el
    float lsum = (ls0 + ls1) + (ls2 + ls3);
    float tot = lsum + __shfl_xor(lsum, 32);
    float inv = 1.f / tot;
    if (hi == 0) Linv[wave][el] = inv;
    __asm__ __volatile__("" ::: "memory");

#pragma unroll
    for (int r = 0; r < 16; r++) {
        int qm = (r & 3) + 8 * (r >> 2) + 4 * hi;
        float iv = Linv[wave][qm];  // broadcast read, conflict-free
        size_t base = ((size_t)(b * SS + q0w + qm)) * (HH * DKK) + h * DKK;
        O[base + el] = bf16b(o0[r] * iv);
        O[base + 32 + el] = bf16b(o1[r] * iv);
    }
}

extern "C" void kernel_launch(void* const* d_in, const int* in_sizes, int n_in,
                              void* d_out, int out_size, void* d_ws, size_t ws_size,
                              hipStream_t stream) {
    const float* hs = (const float*)d_in[0];
    const float* Wq = (const float*)d_in[1];
    const float* Wk = (const float*)d_in[2];
    const float* Wv = (const float*)d_in[3];
    const float* Wo = (const float*)d_in[4];
    const float* rb = (const float*)d_in[5];
    float* out = (float*)d_out;

    char* ws = (char*)d_ws;
    size_t off = 0;
    auto alloc = [&](size_t bytes) -> void* {
        void* p = (void*)(ws + off);
        off += (bytes + 255) & ~(size_t)255;
        return p;
    };
    const size_t M = (size_t)BB * SS; // 4096
    short* hsb = (short*)alloc(M * DD * 2);
    // WqT/WkT/WvT MUST stay contiguous (2MB each, 256-aligned -> no padding):
    // gemm_qkv reads them as one [3072][1024] matrix.
    short* WqT = (short*)alloc((size_t)DD * DD * 2);
    short* WkT = (short*)alloc((size_t)DD * DD * 2);
    short* WvT = (short*)alloc((size_t)DD * DD * 2);
    short* WoT = (short*)alloc((size_t)DD * DD * 2);
    short* Qb  = (short*)alloc(M * DD * 2);
    short* Kb  = (short*)alloc(M * DD * 2);
    short* VTb = (short*)alloc(M * DD * 2);
    short* Ab  = (short*)alloc(M * DD * 2);
    float* btab = (float*)alloc((size_t)HH * 4095 * 4);

    prep<<<8448, 256, 0, stream>>>(hs, Wq, Wk, Wv, Wo, rb,
                                   hsb, WqT, WkT, WvT, WoT, btab);
    gemm_qkv<<<dim3(24, 64), 256, 0, stream>>>(hsb, WqT, Qb, Kb, VTb);
    attn<<<dim3(32, 16), 256, 0, stream>>>(Qb, Kb, VTb, btab, Ab);
    gemm_out<<<dim3(16, 64), 256, 0, stream>>>(Ab, WoT, out);
}

// Round 16
// 187.955 us; speedup vs baseline: 1.2678x; 1.0585x over previous
//
#include <hip/hip_runtime.h>

#define HH 16
#define DKK 64
#define SS 2048
#define BB 2
#define DD 1024

typedef __attribute__((ext_vector_type(4))) float f32x4;
typedef __attribute__((ext_vector_type(16))) float f32x16;
typedef __attribute__((ext_vector_type(8))) short bf16x8;
typedef __attribute__((ext_vector_type(4))) short s16x4;
typedef __attribute__((ext_vector_type(4))) int i32x4;

#define WAITCNT_VM0 0xF70  // vmcnt(0), ignore exp/lgkm

__device__ __forceinline__ short bf16b(float f) {
    union { float f; unsigned u; } x; x.f = f;
    unsigned r = (x.u + 0x7fffu + ((x.u >> 16) & 1u)) >> 16;
    return (short)r;
}

__device__ __forceinline__ f32x4 mfma16(bf16x8 a, bf16x8 b, f32x4 c) {
    return __builtin_amdgcn_mfma_f32_16x16x32_bf16(a, b, c, 0, 0, 0);
}

__device__ __forceinline__ f32x16 mfma32(bf16x8 a, bf16x8 b, f32x16 c) {
    return __builtin_amdgcn_mfma_f32_32x32x16_bf16(a, b, c, 0, 0, 0);
}

__device__ __forceinline__ void lds16(const short* g, short* l) {
    __builtin_amdgcn_global_load_lds(
        (const __attribute__((address_space(1))) void*)g,
        (__attribute__((address_space(3))) void*)l, 16, 0, 0);
}

// pack 2 f32 -> 1 dword of 2 bf16 (RNE)
__device__ __forceinline__ int cvtpk(float lo, float hi) {
    int r;
    asm("v_cvt_pk_bf16_f32 %0, %1, %2" : "=v"(r) : "v"(lo), "v"(hi));
    return r;
}

// swap a's upper 32 lanes with b's lower 32 lanes
__device__ __forceinline__ void swap32(int& a, int& b) {
    asm("v_permlane32_swap_b32 %0, %1" : "+v"(a), "+v"(b));
}

// ---------------- merged prologue: cast + transpose + bias in ONE launch ----------------
// blocks [0,4096): hs fp32->bf16; [4096,8192): weight transpose; [8192,8448): bias.
__global__ __launch_bounds__(256) void prep(
    const float* __restrict__ hs,
    const float* __restrict__ W0, const float* __restrict__ W1,
    const float* __restrict__ W2, const float* __restrict__ W3,
    const float* __restrict__ rb,
    short* __restrict__ hsb,
    short* __restrict__ T0, short* __restrict__ T1,
    short* __restrict__ T2, short* __restrict__ T3,
    float* __restrict__ tab) {
    __shared__ short tile[32][33];
    int blk = blockIdx.x, tid = threadIdx.x;
    if (blk < 4096) {
        int i = (blk * 256 + tid) * 4;
        f32x4 v = *(const f32x4*)(hs + i);
        s16x4 o;
        o.x = bf16b(v.x); o.y = bf16b(v.y); o.z = bf16b(v.z); o.w = bf16b(v.w);
        *(s16x4*)(hsb + i) = o;
    } else if (blk < 8192) {
        int t = blk - 4096;
        int z = t >> 10, r = t & 1023;
        int bx = r & 31, by = r >> 5;
        const float* W; short* T;
        switch (z) {
            case 0: W = W0; T = T0; break;
            case 1: W = W1; T = T1; break;
            case 2: W = W2; T = T2; break;
            default: W = W3; T = T3; break;
        }
        int n0 = bx * 32, k0 = by * 32;
        int tx = tid & 31, ty = (tid >> 5) * 4;
#pragma unroll
        for (int i = 0; i < 4; i++)
            tile[ty + i][tx] = bf16b(W[(k0 + ty + i) * DD + n0 + tx]);
        __syncthreads();
#pragma unroll
        for (int i = 0; i < 4; i++)
            T[(n0 + ty + i) * DD + k0 + tx] = tile[tx][ty + i];
    } else {
        int idx = (blk - 8192) * 256 + tid;
        if (idx < HH * 4095) {
            int h = idx / 4095, d = idx % 4095;
            int rel = d - 2047; // k - q
            int bucket = (rel > 0) ? 16 : 0;
            unsigned rr = (rel < 0) ? (unsigned)(-rel) : (unsigned)rel;
            int add;
            if (rr < 8) add = (int)rr;
            else {
                int e = 31 - __clz(rr);
                unsigned long long r2 = (unsigned long long)rr * (unsigned long long)rr;
                int f = 2 * e + ((r2 >= (2ull << (2 * e))) ? 1 : 0);
                add = 8 + (f - 6);
                if (add > 15) add = 15;
            }
            bucket += add;
            tab[h * 4095 + d] = rb[bucket * HH + h] * 1.44269504f;
        }
    }
}

// ---------------- fused QKV GEMM (r20 measured-best: BK=64, 128x128) -----------------
// Session conclusion: r22's 64x128 tile (6 blocks/CU) regressed non-attn by
// +6us; every TLP/tiling perturbation of this staged-GEMM structure measured
// neutral-to-negative. This BK=64 128x128 config is the measured best
// (total 192.58us). Swizzle verified conflict-free (r21 PMC: 0 conflicts).
__global__ __launch_bounds__(256) void gemm_qkv(
    const short* __restrict__ A, const short* __restrict__ Wt,
    short* __restrict__ Cq, short* __restrict__ Ck, short* __restrict__ Cvt) {
    const int K = 1024;
    __shared__ short As[128 * 64];
    __shared__ short Bs[128 * 64];
    int tid = threadIdx.x;
    int wave = tid >> 6, lane = tid & 63;
    int quad = lane >> 4, l16 = lane & 15;
    int m0 = blockIdx.y * 128, n0 = blockIdx.x * 128;

    int wm = (wave & 1) * 64, wn = (wave >> 1) * 64;
    int r0 = tid >> 3;                         // row 0..31 within 32-row call
    int c0 = ((tid & 7) ^ (r0 & 7)) * 8;       // pre-swizzled global chunk
    int ex7 = l16 & 7;

    f32x4 acc[4][4];
#pragma unroll
    for (int i = 0; i < 4; i++)
#pragma unroll
        for (int j = 0; j < 4; j++) acc[i][j] = (f32x4){0.f, 0.f, 0.f, 0.f};

    for (int k0 = 0; k0 < K; k0 += 64) {
        __syncthreads();
#pragma unroll
        for (int j = 0; j < 4; j++) {
            lds16(A + (size_t)(m0 + j * 32 + r0) * K + k0 + c0,
                  As + j * 2048 + wave * 512);
            lds16(Wt + (size_t)(n0 + j * 32 + r0) * K + k0 + c0,
                  Bs + j * 2048 + wave * 512);
        }
        __syncthreads();
#pragma unroll
        for (int kh = 0; kh < 2; kh++) {
            bf16x8 af[4], bfr[4];
#pragma unroll
            for (int t = 0; t < 4; t++) {
                int sl = (((kh * 4 + quad) ^ ex7)) * 8;
                af[t] = *(const bf16x8*)(As + (wm + t * 16 + l16) * 64 + sl);
                bfr[t] = *(const bf16x8*)(Bs + (wn + t * 16 + l16) * 64 + sl);
            }
#pragma unroll
            for (int mt = 0; mt < 4; mt++)
#pragma unroll
                for (int nt = 0; nt < 4; nt++)
                    acc[mt][nt] = mfma16(af[mt], bfr[nt], acc[mt][nt]);
        }
    }

#pragma unroll
    for (int mt = 0; mt < 4; mt++) {
#pragma unroll
        for (int nt = 0; nt < 4; nt++) {
#pragma unroll
            for (int r = 0; r < 4; r++) {
                int gm = m0 + wm + mt * 16 + quad * 4 + r;
                int gn = n0 + wn + nt * 16 + l16;
                int b = gm >> 11, s = gm & 2047;
                int which = gn >> 10;       // wave-uniform per nt
                int h = (gn >> 6) & 15, dk = gn & 63;
                short bv = bf16b(acc[mt][nt][r]);
                if (which == 0)
                    Cq[(((size_t)(b * HH + h)) * SS + s) * DKK + dk] = bv;
                else if (which == 1)
                    Ck[(((size_t)(b * HH + h)) * SS + s) * DKK + dk] = bv;
                else
                    Cvt[(((size_t)(b * HH + h)) * DKK + dk) * SS + s] = bv;
            }
        }
    }
}

// ---------------- output projection (r20 measured-best: BK=64, 64x128) ---------------
__global__ __launch_bounds__(256) void gemm_out(
    const short* __restrict__ A, const short* __restrict__ Wt,
    float* __restrict__ Cout) {
    const int K = 1024, N = 1024;
    __shared__ short As[64 * 64];
    __shared__ short Bs[128 * 64];
    int tid = threadIdx.x;
    int wave = tid >> 6, lane = tid & 63;
    int quad = lane >> 4, l16 = lane & 15;
    int m0 = blockIdx.y * 64, n0 = blockIdx.x * 128;

    int wm = (wave & 1) * 32, wn = (wave >> 1) * 64;
    int r0 = tid >> 3;
    int c0 = ((tid & 7) ^ (r0 & 7)) * 8;
    int ex7 = l16 & 7;

    f32x4 acc[2][4];
#pragma unroll
    for (int i = 0; i < 2; i++)
#pragma unroll
        for (int j = 0; j < 4; j++) acc[i][j] = (f32x4){0.f, 0.f, 0.f, 0.f};

    for (int k0 = 0; k0 < K; k0 += 64) {
        __syncthreads();
#pragma unroll
        for (int j = 0; j < 2; j++)
            lds16(A + (size_t)(m0 + j * 32 + r0) * K + k0 + c0,
                  As + j * 2048 + wave * 512);
#pragma unroll
        for (int j = 0; j < 4; j++)
            lds16(Wt + (size_t)(n0 + j * 32 + r0) * K + k0 + c0,
                  Bs + j * 2048 + wave * 512);
        __syncthreads();
#pragma unroll
        for (int kh = 0; kh < 2; kh++) {
            bf16x8 af[2], bfr[4];
            int sl = (((kh * 4 + quad) ^ ex7)) * 8;
#pragma unroll
            for (int t = 0; t < 2; t++)
                af[t] = *(const bf16x8*)(As + (wm + t * 16 + l16) * 64 + sl);
#pragma unroll
            for (int t = 0; t < 4; t++)
                bfr[t] = *(const bf16x8*)(Bs + (wn + t * 16 + l16) * 64 + sl);
#pragma unroll
            for (int mt = 0; mt < 2; mt++)
#pragma unroll
                for (int nt = 0; nt < 4; nt++)
                    acc[mt][nt] = mfma16(af[mt], bfr[nt], acc[mt][nt]);
        }
    }

#pragma unroll
    for (int mt = 0; mt < 2; mt++)
#pragma unroll
        for (int nt = 0; nt < 4; nt++)
#pragma unroll
            for (int r = 0; r < 4; r++) {
                int gm = m0 + wm + mt * 16 + quad * 4 + r;
                int gn = n0 + wn + nt * 16 + l16;
                Cout[(size_t)gm * N + gn] = acc[mt][nt][r];
            }
}

// ---------------- attention (r11-exact: verified best; at its latency floor) ---------
__global__ __launch_bounds__(256, 2) void attn(
    const short* __restrict__ Q, const short* __restrict__ Kmat,
    const short* __restrict__ Vt, const float* __restrict__ btab,
    short* __restrict__ O) {
    __shared__ short Ks[2][64 * 64];
    __shared__ short Vs[2][64 * 64];
    __shared__ float Linv[4][32];

    int tid = threadIdx.x;
    int wave = tid >> 6, lane = tid & 63;
    int el = lane & 31, hi = lane >> 5;
    int ex7 = el & 7;
    int bh = blockIdx.x;
    int h = bh & 15, b = bh >> 4;
    int q0b = blockIdx.y * 128;
    int q0w = q0b + wave * 32;

    const short* Qb = Q + (size_t)bh * SS * DKK;
    const short* Kb = Kmat + (size_t)bh * SS * DKK;
    const short* Vb = Vt + (size_t)bh * DKK * SS;
    const float* bt = btab + h * 4095;

    float blo = bt[2047 - 128];
    float bhi = bt[2047 + 128];

    // staging: row kro, 16B slot (tid&7), global slot XOR'd by row&7
    int kro = tid >> 3;
    int gk = (tid & 7) ^ (kro & 7);
    const short* Kg0 = Kb + (size_t)kro * DKK + gk * 8;
    const short* Kg1 = Kb + (size_t)(kro + 32) * DKK + gk * 8;
    const short* Vg0 = Vb + (size_t)kro * SS + gk * 8;
    const short* Vg1 = Vb + (size_t)(kro + 32) * SS + gk * 8;

    // Q as B-fragments (held in registers): lane needs Q[q0w+el][c*16 + hi*8 + j]
    bf16x8 qB[4];
#pragma unroll
    for (int c = 0; c < 4; c++)
        qB[c] = *(const bf16x8*)(Qb + (size_t)(q0w + el) * DKK + c * 16 + hi * 8);

    f32x16 o0, o1;  // dk chunks [0,32) and [32,64); rows = q
#pragma unroll
    for (int i = 0; i < 16; i++) { o0[i] = 0.f; o1[i] = 0.f; }
    float ls0 = 0.f, ls1 = 0.f, ls2 = 0.f, ls3 = 0.f;

    int bq = 2047 - q0w - el;  // bias index base: d = bq + k

    lds16(Kg0, &Ks[0][wave * 512]);
    lds16(Kg1, &Ks[0][2048 + wave * 512]);
    lds16(Vg0, &Vs[0][wave * 512]);
    lds16(Vg1, &Vs[0][2048 + wave * 512]);

    int cur = 0;
    for (int kc = 0; kc < SS; kc += 64) {
        __syncthreads();
        int kn = (kc + 64) & (SS - 1);
        int nxt = cur ^ 1;
        lds16(Kg0 + (size_t)kn * DKK, &Ks[nxt][wave * 512]);
        lds16(Kg1 + (size_t)kn * DKK, &Ks[nxt][2048 + wave * 512]);
        lds16(Vg0 + kn, &Vs[nxt][wave * 512]);
        lds16(Vg1 + kn, &Vs[nxt][2048 + wave * 512]);

        const short* Ksc = &Ks[cur][0];
        const short* Vsc = &Vs[cur][0];

        // V B-fragments: vf[kchunk][m] = V[kchunk*16 + hi*8 + j][m*32 + el]
        bf16x8 vf[4][2];
#pragma unroll
        for (int c4 = 0; c4 < 4; c4++)
#pragma unroll
            for (int m = 0; m < 2; m++)
                vf[c4][m] = *(const bf16x8*)(
                    Vsc + (m * 32 + el) * 64 + (((2 * c4 + hi) ^ ex7) * 8));

#pragma unroll
        for (int st = 0; st < 2; st++) {
            // QK^T for k-strip [kc+st*32, +32): D[k][q], lane col = q = el
            f32x16 acc;
#pragma unroll
            for (int i = 0; i < 16; i++) acc[i] = 0.f;
#pragma unroll
            for (int c = 0; c < 4; c++) {
                bf16x8 kA = *(const bf16x8*)(
                    Ksc + (st * 32 + el) * 64 + (((2 * c + hi) ^ ex7) * 8));
                acc = mfma32(kA, qB[c], acc);
            }

            int ks = kc + st * 32;
            float br[16];
            if (ks > q0w - 159 && ks < q0w + 159) {
                // some |k-q| < 128 possible: read table (index in [1858,2236], safe)
#pragma unroll
                for (int r = 0; r < 16; r++)
                    br[r] = bt[bq + ks + ((r & 3) + 8 * (r >> 2) + 4 * hi)];
            } else {
                float bc = (ks <= q0w - 159) ? blo : bhi;
#pragma unroll
                for (int r = 0; r < 16; r++) br[r] = bc;
            }

            float p[16];
#pragma unroll
            for (int r = 0; r < 16; r++)
                p[r] = __builtin_amdgcn_exp2f(
                    fmaf(acc[r], 1.44269504f, br[r]));
#pragma unroll
            for (int r = 0; r < 16; r += 4) {
                ls0 += p[r]; ls1 += p[r + 1]; ls2 += p[r + 2]; ls3 += p[r + 3];
            }

            // pack own 16 p and swap halves -> PV A-fragments (T12)
            int A1 = cvtpk(p[0], p[1]),   A2 = cvtpk(p[2], p[3]);
            int B1 = cvtpk(p[4], p[5]),   B2 = cvtpk(p[6], p[7]);
            int C1 = cvtpk(p[8], p[9]),   C2 = cvtpk(p[10], p[11]);
            int D1 = cvtpk(p[12], p[13]), D2 = cvtpk(p[14], p[15]);
            swap32(A1, B1); swap32(A2, B2);
            swap32(C1, D1); swap32(C2, D2);
            bf16x8 pf0 = __builtin_bit_cast(bf16x8, (i32x4){A1, A2, B1, B2});
            bf16x8 pf1 = __builtin_bit_cast(bf16x8, (i32x4){C1, C2, D1, D2});

            // PV: o[q][dk] += P[q][k] * V[k][dk]
            o0 = mfma32(pf0, vf[st * 2 + 0][0], o0);
            o1 = mfma32(pf0, vf[st * 2 + 0][1], o1);
            o0 = mfma32(pf1, vf[st * 2 + 1][0], o0);
            o1 = mfma32(pf1, vf[st * 2 + 1][1], o1);
        }
        cur ^= 1;
    }
    __builtin_amdgcn_s_waitcnt(WAITCNT_VM0); // wrapped DMAs land before retirement

    // row sums: lane (el,hi) holds sum over its k-half for q = q0w+el
    float lsum = (ls0 + ls1) + (ls2 + ls3);
    float tot = lsum + __shfl_xor(lsum, 32);
    float inv = 1.f / tot;
    if (hi == 0) Linv[wave][el] = inv;
    __asm__ __volatile__("" ::: "memory");

#pragma unroll
    for (int r = 0; r < 16; r++) {
        int qm = (r & 3) + 8 * (r >> 2) + 4 * hi;
        float iv = Linv[wave][qm];  // broadcast read, conflict-free
        size_t base = ((size_t)(b * SS + q0w + qm)) * (HH * DKK) + h * DKK;
        O[base + el] = bf16b(o0[r] * iv);
        O[base + 32 + el] = bf16b(o1[r] * iv);
    }
}

extern "C" void kernel_launch(void* const* d_in, const int* in_sizes, int n_in,
                              void* d_out, int out_size, void* d_ws, size_t ws_size,
                              hipStream_t stream) {
    const float* hs = (const float*)d_in[0];
    const float* Wq = (const float*)d_in[1];
    const float* Wk = (const float*)d_in[2];
    const float* Wv = (const float*)d_in[3];
    const float* Wo = (const float*)d_in[4];
    const float* rb = (const float*)d_in[5];
    float* out = (float*)d_out;

    char* ws = (char*)d_ws;
    size_t off = 0;
    auto alloc = [&](size_t bytes) -> void* {
        void* p = (void*)(ws + off);
        off += (bytes + 255) & ~(size_t)255;
        return p;
    };
    const size_t M = (size_t)BB * SS; // 4096
    short* hsb = (short*)alloc(M * DD * 2);
    // WqT/WkT/WvT MUST stay contiguous (2MB each, 256-aligned -> no padding):
    // gemm_qkv reads them as one [3072][1024] matrix.
    short* WqT = (short*)alloc((size_t)DD * DD * 2);
    short* WkT = (short*)alloc((size_t)DD * DD * 2);
    short* WvT = (short*)alloc((size_t)DD * DD * 2);
    short* WoT = (short*)alloc((size_t)DD * DD * 2);
    short* Qb  = (short*)alloc(M * DD * 2);
    short* Kb  = (short*)alloc(M * DD * 2);
    short* VTb = (short*)alloc(M * DD * 2);
    short* Ab  = (short*)alloc(M * DD * 2);
    float* btab = (float*)alloc((size_t)HH * 4095 * 4);

    prep<<<8448, 256, 0, stream>>>(hs, Wq, Wk, Wv, Wo, rb,
                                   hsb, WqT, WkT, WvT, WoT, btab);
    gemm_qkv<<<dim3(24, 32), 256, 0, stream>>>(hsb, WqT, Qb, Kb, VTb);
    attn<<<dim3(32, 16), 256, 0, stream>>>(Qb, Kb, VTb, btab, Ab);
    gemm_out<<<dim3(8, 64), 256, 0, stream>>>(Ab, WoT, out);
}